// Round 15
// baseline (97.595 us; speedup 1.0000x reference)
//
#include <hip/hip_runtime.h>
#include <hip/hip_bf16.h>

#define B_ 4
#define NIN_ 32
#define H_ 14
#define W_ 14
#define DIN_ 8
#define NOUT_ 32
#define DOUT_ 16
#define K_ 3
#define OH_ 12
#define OW_ 12
#define PROJ_ 512
#define HID_ 128
#define M_ 288                  // NIN*K*K
#define NPIX_ (B_*NIN_*H_*W_)   // 25088

typedef __attribute__((ext_vector_type(8))) short short8;
typedef __attribute__((ext_vector_type(4))) float f32x4;

__device__ __forceinline__ float bflo(unsigned int u) { return __uint_as_float(u << 16); }
__device__ __forceinline__ float bfhi(unsigned int u) { return __uint_as_float(u & 0xffff0000u); }
__device__ __forceinline__ float bf2f(unsigned short u) { return __uint_as_float(((unsigned int)u) << 16); }
__device__ __forceinline__ unsigned short bfbits(float f) {
    __hip_bfloat16 h = __float2bfloat16(f);
    return *(unsigned short*)&h;
}

// ---------------------------------------------------------------------------
// Prep: W1/W2/W3 f32 -> bf16 in MFMA B-fragment order.  (unchanged)
// ---------------------------------------------------------------------------
__global__ __launch_bounds__(256) void prep_kernel(
    const float* __restrict__ W1, const float* __restrict__ W2,
    const float* __restrict__ W3,
    __hip_bfloat16* __restrict__ W1B, __hip_bfloat16* __restrict__ W2B,
    __hip_bfloat16* __restrict__ W3B)
{
    int idx = blockIdx.x * 256 + threadIdx.x;  // [0, 65536)
    {
        int j = idx & 7, lane = (idx >> 3) & 63, kt = (idx >> 9) & 15, nt = idx >> 13;
        int k = kt * 32 + (lane >> 4) * 8 + j;
        int c = nt * 16 + (lane & 15);
        W2B[idx] = __float2bfloat16(W2[k * HID_ + c]);
    }
    {
        int j = idx & 7, lane = (idx >> 3) & 63, kt = (idx >> 9) & 3, nt = idx >> 11;
        int k = kt * 32 + (lane >> 4) * 8 + j;
        int c = nt * 16 + (lane & 15);
        W3B[idx] = __float2bfloat16(W3[k * PROJ_ + c]);
    }
    if (idx < 16384) {
        int j = idx & 7, lane = (idx >> 3) & 63, nt = idx >> 9;
        int c = nt * 16 + (lane & 15);          // k = (lane>>4)*8 + j, real iff lane<16
        W1B[idx] = (lane < 16) ? __float2bfloat16(W1[j * PROJ_ + c])
                               : __float2bfloat16(0.f);
    }
}

// ---------------------------------------------------------------------------
// Fused MLP, 32 pixels/block, 256 threads, wave = n-quarter over both m-tiles.
// NEW: stage-3 epilogue stages the 32x512 bf16 U-tile in LDS ([32][520] pad,
// 33.3 KB overlaid after h2A reads) then stores coalesced uint4 — replaces
// 64 quarter-coalesced 2-byte stores/thread with 8x 16B stores.
// ---------------------------------------------------------------------------
__global__ __launch_bounds__(256) void mlp_mfma_kernel(
    const float* __restrict__ x,
    const short8* __restrict__ W1B, const float* __restrict__ b1,
    const short8* __restrict__ W2B, const float* __restrict__ b2,
    const short8* __restrict__ W3B, const float* __restrict__ b3,
    __hip_bfloat16* __restrict__ U)
{
    __shared__ short smem[17408];          // h1A 16384sh | A16 1024sh | Ust overlay
    short* h1A = smem;                     // [mt2][kt16][64][8]
    short* A16 = smem + 16384;             // [mt2][64][8]

    const int t = threadIdx.x;
    const int pix0 = blockIdx.x * 32;
    const int l = t & 63, wv = t >> 6;     // wv 0..3 = n-quarter
    const int r0 = (l >> 4) * 4;

    // ---- stage A16: x -> bf16 A-frag (both m-tiles, threads 0..127) ----
    if (t < 128) {
        int mt2 = t >> 6, ln = t & 63;
        unsigned int* d32 = (unsigned int*)(A16 + (mt2 * 64 + ln) * 8);
        if (ln < 16) {
            const float* xr = &x[(size_t)(pix0 + mt2 * 16 + ln) * DIN_];
            float4 xa = *(const float4*)xr;
            float4 xb = *(const float4*)(xr + 4);
            d32[0] = (unsigned int)bfbits(xa.x) | ((unsigned int)bfbits(xa.y) << 16);
            d32[1] = (unsigned int)bfbits(xa.z) | ((unsigned int)bfbits(xa.w) << 16);
            d32[2] = (unsigned int)bfbits(xb.x) | ((unsigned int)bfbits(xb.y) << 16);
            d32[3] = (unsigned int)bfbits(xb.z) | ((unsigned int)bfbits(xb.w) << 16);
        } else {
            d32[0] = 0u; d32[1] = 0u; d32[2] = 0u; d32[3] = 0u;
        }
    }
    __syncthreads();

    // ---- stage 1: h1 = relu(x @ W1 + b1); wave: nts [wv*8, wv*8+8), both mts ----
    {
        const short8* A16f = (const short8*)A16;
        short8 am0 = A16f[l];
        short8 am1 = A16f[64 + l];
        #pragma unroll
        for (int nt2 = 0; nt2 < 8; ++nt2) {
            int nt = wv * 8 + nt2;
            short8 bfr = W1B[nt * 64 + l];
            f32x4 ac0 = (f32x4){0.f, 0.f, 0.f, 0.f};
            f32x4 ac1 = (f32x4){0.f, 0.f, 0.f, 0.f};
            ac0 = __builtin_amdgcn_mfma_f32_16x16x32_bf16(am0, bfr, ac0, 0, 0, 0);
            ac1 = __builtin_amdgcn_mfma_f32_16x16x32_bf16(am1, bfr, ac1, 0, 0, 0);
            int c = nt * 16 + (l & 15);
            float bb = b1[c];
            int kt = c >> 5, hi = (c >> 3) & 3;
            #pragma unroll
            for (int q = 0; q < 4; ++q) {
                int base = (kt * 64 + hi * 16 + r0 + q) * 8 + (c & 7);
                h1A[base]        = (short)bfbits(fmaxf(ac0[q] + bb, 0.f));
                h1A[base + 8192] = (short)bfbits(fmaxf(ac1[q] + bb, 0.f));
            }
        }
    }
    __syncthreads();

    // ---- stage 2: h2 = relu(h1 @ W2 + b2); wave: nts [wv*2, wv*2+2), both mts ----
    f32x4 acc2[2][2];
    {
        const short8* h1f = (const short8*)h1A;
        #pragma unroll
        for (int mt = 0; mt < 2; ++mt)
            #pragma unroll
            for (int nt2 = 0; nt2 < 2; ++nt2)
                acc2[mt][nt2] = (f32x4){0.f, 0.f, 0.f, 0.f};
        for (int ktk = 0; ktk < 16; ++ktk) {
            short8 am0 = h1f[ktk * 64 + l];
            short8 am1 = h1f[(16 + ktk) * 64 + l];
            #pragma unroll
            for (int nt2 = 0; nt2 < 2; ++nt2) {
                short8 bfr = W2B[((wv * 2 + nt2) * 16 + ktk) * 64 + l];
                acc2[0][nt2] = __builtin_amdgcn_mfma_f32_16x16x32_bf16(am0, bfr, acc2[0][nt2], 0, 0, 0);
                acc2[1][nt2] = __builtin_amdgcn_mfma_f32_16x16x32_bf16(am1, bfr, acc2[1][nt2], 0, 0, 0);
            }
        }
    }
    __syncthreads();                  // all h1A reads done; overlay h2A
    short* h2A = smem;                // [mt2][kt3 4][64][8] = 8 KB
    {
        #pragma unroll
        for (int mt = 0; mt < 2; ++mt)
            #pragma unroll
            for (int nt2 = 0; nt2 < 2; ++nt2) {
                int nt = wv * 2 + nt2;
                int c = nt * 16 + (l & 15);
                float bb = b2[c];
                int kt3 = c >> 5;
                int lane3base = ((c >> 3) & 3) * 16;
                #pragma unroll
                for (int q = 0; q < 4; ++q) {
                    float v = fmaxf(acc2[mt][nt2][q] + bb, 0.f);
                    int flat = ((mt * 4 + kt3) * 64 + lane3base + r0 + q) * 8 + (c & 7);
                    h2A[flat] = (short)bfbits(v);
                }
            }
    }
    __syncthreads();

    // ---- stage 3: U = h2 @ W3 + b3; LDS-staged coalesced epilogue ----
    {
        const short8* h2f = (const short8*)h2A;
        short8 a[2][4];
        #pragma unroll
        for (int mt = 0; mt < 2; ++mt)
            #pragma unroll
            for (int ktk = 0; ktk < 4; ++ktk)
                a[mt][ktk] = h2f[(mt * 4 + ktk) * 64 + l];
        __syncthreads();              // h2A reads done; overlay Ust
        short* Ust = smem;            // [32][520] bf16 = 33.3 KB

        for (int pass = 0; pass < 2; ++pass) {
            f32x4 acc[2][4];
            #pragma unroll
            for (int mt = 0; mt < 2; ++mt)
                #pragma unroll
                for (int nt2 = 0; nt2 < 4; ++nt2)
                    acc[mt][nt2] = (f32x4){0.f, 0.f, 0.f, 0.f};
            #pragma unroll
            for (int nt2 = 0; nt2 < 4; ++nt2) {
                int nt = wv * 8 + pass * 4 + nt2;
                #pragma unroll
                for (int ktk = 0; ktk < 4; ++ktk) {
                    short8 bfr = W3B[(nt * 4 + ktk) * 64 + l];
                    acc[0][nt2] = __builtin_amdgcn_mfma_f32_16x16x32_bf16(a[0][ktk], bfr, acc[0][nt2], 0, 0, 0);
                    acc[1][nt2] = __builtin_amdgcn_mfma_f32_16x16x32_bf16(a[1][ktk], bfr, acc[1][nt2], 0, 0, 0);
                }
            }
            #pragma unroll
            for (int mt = 0; mt < 2; ++mt)
                #pragma unroll
                for (int nt2 = 0; nt2 < 4; ++nt2) {
                    int c = (wv * 8 + pass * 4 + nt2) * 16 + (l & 15);
                    float bb = b3[c];
                    #pragma unroll
                    for (int q = 0; q < 4; ++q)
                        Ust[(mt * 16 + r0 + q) * 520 + c] =
                            (short)bfbits(acc[mt][nt2][q] + bb);
                }
        }
        __syncthreads();

        // coalesced store: 2048 uint4 (32 px x 64), 8 per thread; per wave px
        // is fixed so lanes write consecutive 16B -> 1KB/instruction.
        const unsigned int* Uw = (const unsigned int*)Ust;
        unsigned int* Ug = (unsigned int*)U;
        #pragma unroll
        for (int rep = 0; rep < 8; ++rep) {
            int idx = rep * 256 + t;
            int px = idx >> 6, q = idx & 63;
            int so = px * 260 + q * 4;          // u32 index into Ust (520 sh = 260 u32)
            uint4 v;
            v.x = Uw[so]; v.y = Uw[so + 1]; v.z = Uw[so + 2]; v.w = Uw[so + 3];
            *(uint4*)(Ug + ((size_t)(pix0 + px) * 256 + q * 4)) = v;
        }
    }
}

// ---------------------------------------------------------------------------
// SumN: SumN[b,y,x,ch] = sum_n U[b,n,y,x,ch]  (bf16 out).  Vectorized uint4:
// 1 wave/position, lane = one 16B chunk (8 ch), unroll-4 for load ILP.
// ---------------------------------------------------------------------------
__global__ __launch_bounds__(64) void sumn_kernel(
    const uint4* __restrict__ U4, uint4* __restrict__ SumN4)
{
    const int byx = blockIdx.x;            // b*196 + yx
    const int b = byx / 196, yx = byx % 196;
    const int t = threadIdx.x;             // 0..63: uint4 index within row
    const uint4* p = U4 + ((size_t)(b * NIN_) * 196 + yx) * 64 + t;
    float a0=0,a1=0,a2=0,a3=0,a4=0,a5=0,a6=0,a7=0;
    #pragma unroll 4
    for (int n = 0; n < NIN_; ++n) {
        uint4 u = p[(size_t)n * 196 * 64];
        a0 += bflo(u.x); a1 += bfhi(u.x);
        a2 += bflo(u.y); a3 += bfhi(u.y);
        a4 += bflo(u.z); a5 += bfhi(u.z);
        a6 += bflo(u.w); a7 += bfhi(u.w);
    }
    uint4 o;
    o.x = (unsigned int)bfbits(a0) | ((unsigned int)bfbits(a1) << 16);
    o.y = (unsigned int)bfbits(a2) | ((unsigned int)bfbits(a3) << 16);
    o.z = (unsigned int)bfbits(a4) | ((unsigned int)bfbits(a5) << 16);
    o.w = (unsigned int)bfbits(a6) | ((unsigned int)bfbits(a7) << 16);
    SumN4[(size_t)byx * 64 + t] = o;
}

// ---------------------------------------------------------------------------
// Routing — R10 2-chain structure + exp2 rebase (unchanged from R13/R14).
// VGPR <=64 keeps all 576 blocks co-resident (R12: 72 VGPR -> cliff).
// ---------------------------------------------------------------------------
__global__ __launch_bounds__(512) void route_kernel(
    const __hip_bfloat16* __restrict__ Ub,
    const unsigned short* __restrict__ SumNb,
    float* __restrict__ out_v,    // (B, NOUT, OH, OW, DOUT)
    float* __restrict__ out_ent)  // (B, M, 1, OH, OW)
{
    const uint4* __restrict__ U4 = (const uint4*)Ub;

    __shared__ int   pixoff[M_];
    __shared__ float sredT[8][16][33];   // [wave][d][no]  16.9 KB
    __shared__ float sbufT[16][33];      // [d][no]
    __shared__ float vvT[16][33];        // [d][no]
    __shared__ float scl[NOUT_];

    const int bid = blockIdx.x;
    const int xcd = bid & 7, sub = bid >> 3;   // XCD-clustered: 2 XCDs per b
    const int b  = xcd >> 1;
    const int ij = (xcd & 1) * 72 + sub;
    const int i  = ij / OW_, j = ij % OW_;
    const int t  = threadIdx.x;
    const int l  = t & 63, wv = t >> 6;        // wv 0..7
    const int no = l & 31, half = l >> 5;
    const float LOG2E = 1.4426950408889634f;

    if (t < M_) {
        int n = t / 9, r = t % 9, ki = r / 3, kj = r % 3;
        pixoff[t] = ((b * NIN_ + n) * H_ + (i + ki)) * W_ + (j + kj);
    }
    // s0 = (1/32) * 3x3 box-sum of SumN
    {
        float s = 0.f;
        const int base = b * 196;
        #pragma unroll
        for (int ki = 0; ki < 3; ++ki)
            #pragma unroll
            for (int kj = 0; kj < 3; ++kj)
                s += bf2f(SumNb[(size_t)(base + (i + ki) * 14 + (j + kj)) * 512 + t]);
        sbufT[t & 15][t >> 4] = s * (1.f / 32.f);
    }
    __syncthreads();
    if (t < NOUT_) {
        float ns = 0.f;
        #pragma unroll
        for (int d = 0; d < DOUT_; ++d) { float s = sbufT[d][t]; ns += s * s; }
        scl[t] = ns / (1.f + ns) * rsqrtf(ns + 1e-16f);
    }
    __syncthreads();
    vvT[t >> 5][t & 31] = sbufT[t >> 5][t & 31] * scl[t & 31];
    __syncthreads();

    float vr[16];
    #pragma unroll
    for (int k = 0; k < 16; ++k) vr[k] = vvT[k][no] * LOG2E;   // log2e * v0

    const int mbase = wv * 36;

// one row: unpack -> dot (dp in log2 units) -> exp2 -> butterfly -> s-acc
#define PROC_ROW(Q0, Q1, ROWIDX)                                              \
    {                                                                         \
        float pv[16];                                                         \
        pv[0]=bflo(Q0.x);  pv[1]=bfhi(Q0.x);  pv[2]=bflo(Q0.y);  pv[3]=bfhi(Q0.y);   \
        pv[4]=bflo(Q0.z);  pv[5]=bfhi(Q0.z);  pv[6]=bflo(Q0.w);  pv[7]=bfhi(Q0.w);   \
        pv[8]=bflo(Q1.x);  pv[9]=bfhi(Q1.x);  pv[10]=bflo(Q1.y); pv[11]=bfhi(Q1.y);  \
        pv[12]=bflo(Q1.z); pv[13]=bfhi(Q1.z); pv[14]=bflo(Q1.w); pv[15]=bfhi(Q1.w);  \
        float d0 = pv[0]*vr[0] + pv[4]*vr[4] + pv[8]*vr[8]  + pv[12]*vr[12];  \
        float d1 = pv[1]*vr[1] + pv[5]*vr[5] + pv[9]*vr[9]  + pv[13]*vr[13];  \
        float d2 = pv[2]*vr[2] + pv[6]*vr[6] + pv[10]*vr[10]+ pv[14]*vr[14];  \
        float d3 = pv[3]*vr[3] + pv[7]*vr[7] + pv[11]*vr[11]+ pv[15]*vr[15];  \
        float dp = (d0 + d1) + (d2 + d3);                                     \
        float e = exp2f(dp);                                                  \
        float S = e;                                                          \
        if (pass == 2) {                                                      \
            float E = e * dp;                                                 \
            _Pragma("unroll")                                                 \
            for (int msk = 16; msk >= 1; msk >>= 1) {                         \
                S += __shfl_xor(S, msk);                                      \
                E += __shfl_xor(E, msk);                                      \
            }                                                                 \
            if (no == 0)                                                      \
                out_ent[(b * M_ + (mbase + (ROWIDX))) * (OH_ * OW_) + ij] =   \
                    0.2f * (log2f(S) - E / S);                                \
            float cc = e * __frcp_rn(S);                                      \
            _Pragma("unroll")                                                 \
            for (int k = 0; k < 16; ++k) s_acc[k] += cc * pv[k];              \
        } else {                                                              \
            _Pragma("unroll")                                                 \
            for (int msk = 16; msk >= 1; msk >>= 1)                           \
                S += __shfl_xor(S, msk);                                      \
            float cc = e * __frcp_rn(S);                                      \
            _Pragma("unroll")                                                 \
            for (int k = 0; k < 16; ++k) s_acc[k] += cc * pv[k];              \
        }                                                                     \
    }

    for (int pass = 1; pass <= 2; ++pass) {
        float s_acc[16];
        #pragma unroll
        for (int k = 0; k < 16; ++k) s_acc[k] = 0.f;

        // preload pair g=0: rows half and 2+half
        uint4 c00, c01, c10, c11;
        {
            size_t ba = (size_t)pixoff[mbase + half] * 64 + no * 2;
            c00 = U4[ba]; c01 = U4[ba + 1];
            size_t bb2 = (size_t)pixoff[mbase + 2 + half] * 64 + no * 2;
            c10 = U4[bb2]; c11 = U4[bb2 + 1];
        }
        #pragma clang loop unroll(disable)
        for (int g = 0; g < 9; ++g) {
            uint4 n00 = c00, n01 = c01, n10 = c10, n11 = c11;
            if (g + 1 < 9) {
                size_t ba = (size_t)pixoff[mbase + 4 * (g + 1) + half] * 64 + no * 2;
                n00 = U4[ba]; n01 = U4[ba + 1];
                size_t bb2 = (size_t)pixoff[mbase + 4 * (g + 1) + 2 + half] * 64 + no * 2;
                n10 = U4[bb2]; n11 = U4[bb2 + 1];
            }
            PROC_ROW(c00, c01, 4 * g + half);
            PROC_ROW(c10, c11, 4 * g + 2 + half);
            c00 = n00; c01 = n01; c10 = n10; c11 = n11;
        }

        // wave-internal combine (lane l and l+32 share no), then LDS reduce
        #pragma unroll
        for (int k = 0; k < 16; ++k) s_acc[k] += __shfl_xor(s_acc[k], 32);
        if (half == 0) {
            #pragma unroll
            for (int k = 0; k < 16; ++k) sredT[wv][k][no] = s_acc[k];
        }
        __syncthreads();
        {
            int d = t >> 5, n2 = t & 31;
            float ssm = 0.f;
            #pragma unroll
            for (int h2 = 0; h2 < 8; ++h2) ssm += sredT[h2][d][n2];
            sbufT[d][n2] = ssm;
        }
        __syncthreads();
        if (t < NOUT_) {
            float ns = 0.f;
            #pragma unroll
            for (int d = 0; d < DOUT_; ++d) { float s = sbufT[d][t]; ns += s * s; }
            scl[t] = ns / (1.f + ns) * rsqrtf(ns + 1e-16f);
        }
        __syncthreads();
        vvT[t >> 5][t & 31] = sbufT[t >> 5][t & 31] * scl[t & 31];
        __syncthreads();

        if (pass == 1) {
            #pragma unroll
            for (int k = 0; k < 16; ++k) vr[k] += vvT[k][no] * LOG2E;  // log2e*(v0+v1)
        }
    }
#undef PROC_ROW

    {   // final v output (vvT holds v2)
        int no2 = t >> 4, d = t & 15;
        out_v[(((b * NOUT_ + no2) * OH_ + i) * OW_ + j) * DOUT_ + d] = vvT[d][no2];
    }
}

extern "C" void kernel_launch(void* const* d_in, const int* in_sizes, int n_in,
                              void* d_out, int out_size, void* d_ws, size_t ws_size,
                              hipStream_t stream) {
    const float* x  = (const float*)d_in[0];
    const float* W1 = (const float*)d_in[1];
    const float* b1 = (const float*)d_in[2];
    const float* W2 = (const float*)d_in[3];
    const float* b2 = (const float*)d_in[4];
    const float* W3 = (const float*)d_in[5];
    const float* b3 = (const float*)d_in[6];

    // ws: U (25,690,112 B) | W2B (131,072) | W3B (131,072) | W1B (32,768) | SumN (802,816)
    char* ws = (char*)d_ws;
    __hip_bfloat16* U   = (__hip_bfloat16*)ws;
    __hip_bfloat16* W2B = (__hip_bfloat16*)(ws + (size_t)NPIX_ * PROJ_ * 2);
    __hip_bfloat16* W3B = W2B + (size_t)PROJ_ * HID_;
    __hip_bfloat16* W1B = W3B + (size_t)PROJ_ * HID_;
    unsigned int*   SumNb = (unsigned int*)(W1B + 16384);

    float* out_v   = (float*)d_out;
    float* out_ent = out_v + (size_t)B_ * NOUT_ * OH_ * OW_ * DOUT_;

    hipLaunchKernelGGL(prep_kernel, dim3(256), dim3(256), 0, stream,
                       W1, W2, W3, W1B, W2B, W3B);
    hipLaunchKernelGGL(mlp_mfma_kernel, dim3(NPIX_ / 32), dim3(256), 0, stream,
                       x, (const short8*)W1B, b1, (const short8*)W2B, b2,
                       (const short8*)W3B, b3, U);
    hipLaunchKernelGGL(sumn_kernel, dim3(B_ * H_ * W_), dim3(64), 0, stream,
                       (const uint4*)U, (uint4*)SumNb);
    hipLaunchKernelGGL(route_kernel, dim3(B_ * OH_ * OW_), dim3(512), 0, stream,
                       U, (const unsigned short*)SumNb, out_v, out_ent);
}

// Round 16
// 90.102 us; speedup vs baseline: 1.0832x; 1.0832x over previous
//
#include <hip/hip_runtime.h>
#include <hip/hip_bf16.h>

#define B_ 4
#define NIN_ 32
#define H_ 14
#define W_ 14
#define DIN_ 8
#define NOUT_ 32
#define DOUT_ 16
#define K_ 3
#define OH_ 12
#define OW_ 12
#define PROJ_ 512
#define HID_ 128
#define M_ 288                  // NIN*K*K
#define NPIX_ (B_*NIN_*H_*W_)   // 25088

typedef __attribute__((ext_vector_type(8))) short short8;
typedef __attribute__((ext_vector_type(4))) float f32x4;

__device__ __forceinline__ float bflo(unsigned int u) { return __uint_as_float(u << 16); }
__device__ __forceinline__ float bfhi(unsigned int u) { return __uint_as_float(u & 0xffff0000u); }
__device__ __forceinline__ float bf2f(unsigned short u) { return __uint_as_float(((unsigned int)u) << 16); }
__device__ __forceinline__ unsigned short bfbits(float f) {
    __hip_bfloat16 h = __float2bfloat16(f);
    return *(unsigned short*)&h;
}

// ---------------------------------------------------------------------------
// Prep: W1/W2/W3 f32 -> bf16 in MFMA B-fragment order.
// ---------------------------------------------------------------------------
__global__ __launch_bounds__(256) void prep_kernel(
    const float* __restrict__ W1, const float* __restrict__ W2,
    const float* __restrict__ W3,
    __hip_bfloat16* __restrict__ W1B, __hip_bfloat16* __restrict__ W2B,
    __hip_bfloat16* __restrict__ W3B)
{
    int idx = blockIdx.x * 256 + threadIdx.x;  // [0, 65536)
    {
        int j = idx & 7, lane = (idx >> 3) & 63, kt = (idx >> 9) & 15, nt = idx >> 13;
        int k = kt * 32 + (lane >> 4) * 8 + j;
        int c = nt * 16 + (lane & 15);
        W2B[idx] = __float2bfloat16(W2[k * HID_ + c]);
    }
    {
        int j = idx & 7, lane = (idx >> 3) & 63, kt = (idx >> 9) & 3, nt = idx >> 11;
        int k = kt * 32 + (lane >> 4) * 8 + j;
        int c = nt * 16 + (lane & 15);
        W3B[idx] = __float2bfloat16(W3[k * PROJ_ + c]);
    }
    if (idx < 16384) {
        int j = idx & 7, lane = (idx >> 3) & 63, nt = idx >> 9;
        int c = nt * 16 + (lane & 15);          // k = (lane>>4)*8 + j, real iff lane<16
        W1B[idx] = (lane < 16) ? __float2bfloat16(W1[j * PROJ_ + c])
                               : __float2bfloat16(0.f);
    }
}

// ---------------------------------------------------------------------------
// Fused MLP, 32 pixels/block, 256 threads, wave = n-quarter over both m-tiles
// (R14 configuration — measured best.  R15's LDS-staged epilogue regressed:
// extra barrier + LDS round-trip cost more than the store coalescing saved.)
// ---------------------------------------------------------------------------
__global__ __launch_bounds__(256) void mlp_mfma_kernel(
    const float* __restrict__ x,
    const short8* __restrict__ W1B, const float* __restrict__ b1,
    const short8* __restrict__ W2B, const float* __restrict__ b2,
    const short8* __restrict__ W3B, const float* __restrict__ b3,
    __hip_bfloat16* __restrict__ U)
{
    __shared__ short smem[17408];          // h1A 16384 | A16 1024 (34.8 KB)
    short* h1A = smem;                     // [mt2][kt16][64][8]
    short* A16 = smem + 16384;             // [mt2][64][8]

    const int t = threadIdx.x;
    const int pix0 = blockIdx.x * 32;
    const int l = t & 63, wv = t >> 6;     // wv 0..3 = n-quarter
    const int r0 = (l >> 4) * 4;

    // ---- stage A16: x -> bf16 A-frag (both m-tiles, threads 0..127) ----
    if (t < 128) {
        int mt2 = t >> 6, ln = t & 63;
        unsigned int* d32 = (unsigned int*)(A16 + (mt2 * 64 + ln) * 8);
        if (ln < 16) {
            const float* xr = &x[(size_t)(pix0 + mt2 * 16 + ln) * DIN_];
            float4 xa = *(const float4*)xr;
            float4 xb = *(const float4*)(xr + 4);
            d32[0] = (unsigned int)bfbits(xa.x) | ((unsigned int)bfbits(xa.y) << 16);
            d32[1] = (unsigned int)bfbits(xa.z) | ((unsigned int)bfbits(xa.w) << 16);
            d32[2] = (unsigned int)bfbits(xb.x) | ((unsigned int)bfbits(xb.y) << 16);
            d32[3] = (unsigned int)bfbits(xb.z) | ((unsigned int)bfbits(xb.w) << 16);
        } else {
            d32[0] = 0u; d32[1] = 0u; d32[2] = 0u; d32[3] = 0u;
        }
    }
    __syncthreads();

    // ---- stage 1: h1 = relu(x @ W1 + b1); wave: nts [wv*8, wv*8+8), both mts ----
    {
        const short8* A16f = (const short8*)A16;
        short8 am0 = A16f[l];
        short8 am1 = A16f[64 + l];
        #pragma unroll
        for (int nt2 = 0; nt2 < 8; ++nt2) {
            int nt = wv * 8 + nt2;
            short8 bfr = W1B[nt * 64 + l];
            f32x4 ac0 = (f32x4){0.f, 0.f, 0.f, 0.f};
            f32x4 ac1 = (f32x4){0.f, 0.f, 0.f, 0.f};
            ac0 = __builtin_amdgcn_mfma_f32_16x16x32_bf16(am0, bfr, ac0, 0, 0, 0);
            ac1 = __builtin_amdgcn_mfma_f32_16x16x32_bf16(am1, bfr, ac1, 0, 0, 0);
            int c = nt * 16 + (l & 15);
            float bb = b1[c];
            int kt = c >> 5, hi = (c >> 3) & 3;
            #pragma unroll
            for (int q = 0; q < 4; ++q) {
                int base = (kt * 64 + hi * 16 + r0 + q) * 8 + (c & 7);
                h1A[base]        = (short)bfbits(fmaxf(ac0[q] + bb, 0.f));
                h1A[base + 8192] = (short)bfbits(fmaxf(ac1[q] + bb, 0.f));
            }
        }
    }
    __syncthreads();

    // ---- stage 2: h2 = relu(h1 @ W2 + b2); wave: nts [wv*2, wv*2+2), both mts ----
    f32x4 acc2[2][2];
    {
        const short8* h1f = (const short8*)h1A;
        #pragma unroll
        for (int mt = 0; mt < 2; ++mt)
            #pragma unroll
            for (int nt2 = 0; nt2 < 2; ++nt2)
                acc2[mt][nt2] = (f32x4){0.f, 0.f, 0.f, 0.f};
        for (int ktk = 0; ktk < 16; ++ktk) {
            short8 am0 = h1f[ktk * 64 + l];
            short8 am1 = h1f[(16 + ktk) * 64 + l];
            #pragma unroll
            for (int nt2 = 0; nt2 < 2; ++nt2) {
                short8 bfr = W2B[((wv * 2 + nt2) * 16 + ktk) * 64 + l];
                acc2[0][nt2] = __builtin_amdgcn_mfma_f32_16x16x32_bf16(am0, bfr, acc2[0][nt2], 0, 0, 0);
                acc2[1][nt2] = __builtin_amdgcn_mfma_f32_16x16x32_bf16(am1, bfr, acc2[1][nt2], 0, 0, 0);
            }
        }
    }
    __syncthreads();                  // all h1A reads done; overlay h2A
    short* h2A = smem;                // [mt2][kt3 4][64][8] = 8 KB
    {
        #pragma unroll
        for (int mt = 0; mt < 2; ++mt)
            #pragma unroll
            for (int nt2 = 0; nt2 < 2; ++nt2) {
                int nt = wv * 2 + nt2;
                int c = nt * 16 + (l & 15);
                float bb = b2[c];
                int kt3 = c >> 5;
                int lane3base = ((c >> 3) & 3) * 16;
                #pragma unroll
                for (int q = 0; q < 4; ++q) {
                    float v = fmaxf(acc2[mt][nt2][q] + bb, 0.f);
                    int flat = ((mt * 4 + kt3) * 64 + lane3base + r0 + q) * 8 + (c & 7);
                    h2A[flat] = (short)bfbits(v);
                }
            }
    }
    __syncthreads();

    // ---- stage 3: U = h2 @ W3 + b3; wave: nts [wv*8, wv*8+8), both mts ----
    {
        const short8* h2f = (const short8*)h2A;
        short8 a[2][4];
        #pragma unroll
        for (int mt = 0; mt < 2; ++mt)
            #pragma unroll
            for (int ktk = 0; ktk < 4; ++ktk)
                a[mt][ktk] = h2f[(mt * 4 + ktk) * 64 + l];
        for (int pass = 0; pass < 2; ++pass) {
            f32x4 acc[2][4];
            #pragma unroll
            for (int mt = 0; mt < 2; ++mt)
                #pragma unroll
                for (int nt2 = 0; nt2 < 4; ++nt2)
                    acc[mt][nt2] = (f32x4){0.f, 0.f, 0.f, 0.f};
            #pragma unroll
            for (int nt2 = 0; nt2 < 4; ++nt2) {
                int nt = wv * 8 + pass * 4 + nt2;
                #pragma unroll
                for (int ktk = 0; ktk < 4; ++ktk) {
                    short8 bfr = W3B[(nt * 4 + ktk) * 64 + l];
                    acc[0][nt2] = __builtin_amdgcn_mfma_f32_16x16x32_bf16(a[0][ktk], bfr, acc[0][nt2], 0, 0, 0);
                    acc[1][nt2] = __builtin_amdgcn_mfma_f32_16x16x32_bf16(a[1][ktk], bfr, acc[1][nt2], 0, 0, 0);
                }
            }
            #pragma unroll
            for (int mt = 0; mt < 2; ++mt)
                #pragma unroll
                for (int nt2 = 0; nt2 < 4; ++nt2) {
                    int c = (wv * 8 + pass * 4 + nt2) * 16 + (l & 15);
                    float bb = b3[c];
                    #pragma unroll
                    for (int q = 0; q < 4; ++q) {
                        U[(size_t)(pix0 + mt * 16 + r0 + q) * PROJ_ + c] =
                            __float2bfloat16(acc[mt][nt2][q] + bb);
                    }
                }
        }
    }
}

// ---------------------------------------------------------------------------
// SumN: SumN[b,y,x,ch] = sum_n U[b,n,y,x,ch]  (bf16 out).  One pass over U.
// (R14 256-thread version — R15's 64-thread uint4 variant regressed.)
// ---------------------------------------------------------------------------
__global__ __launch_bounds__(256) void sumn_kernel(
    const unsigned int* __restrict__ U32, unsigned int* __restrict__ SumNb)
{
    const int byx = blockIdx.x;            // b*196 + yx
    const int b = byx / 196, yx = byx % 196;
    const int t = threadIdx.x;
    const unsigned int* p = U32 + ((size_t)(b * NIN_) * 196 + yx) * 256 + t;
    float a0 = 0.f, a1 = 0.f;
    #pragma unroll 8
    for (int n = 0; n < NIN_; ++n) {
        unsigned int u = p[(size_t)n * 196 * 256];
        a0 += bflo(u); a1 += bfhi(u);
    }
    SumNb[(size_t)byx * 256 + t] =
        (unsigned int)bfbits(a0) | ((unsigned int)bfbits(a1) << 16);
}

// ---------------------------------------------------------------------------
// Routing — R10/R14 2-chain structure + exp2 rebase.  NEW: fast v_rcp_f32
// (__builtin_amdgcn_rcpf, ~1 ulp) instead of __frcp_rn's Newton sequence in
// the hot chain (cc feeds bf16-precision sums; threshold 2e-2).
// VGPR <=64 keeps all 576 blocks co-resident (R12: 72 VGPR -> cliff).
// ---------------------------------------------------------------------------
__global__ __launch_bounds__(512) void route_kernel(
    const __hip_bfloat16* __restrict__ Ub,
    const unsigned short* __restrict__ SumNb,
    float* __restrict__ out_v,    // (B, NOUT, OH, OW, DOUT)
    float* __restrict__ out_ent)  // (B, M, 1, OH, OW)
{
    const uint4* __restrict__ U4 = (const uint4*)Ub;

    __shared__ int   pixoff[M_];
    __shared__ float sredT[8][16][33];   // [wave][d][no]  16.9 KB
    __shared__ float sbufT[16][33];      // [d][no]
    __shared__ float vvT[16][33];        // [d][no]
    __shared__ float scl[NOUT_];

    const int bid = blockIdx.x;
    const int xcd = bid & 7, sub = bid >> 3;   // XCD-clustered: 2 XCDs per b
    const int b  = xcd >> 1;
    const int ij = (xcd & 1) * 72 + sub;
    const int i  = ij / OW_, j = ij % OW_;
    const int t  = threadIdx.x;
    const int l  = t & 63, wv = t >> 6;        // wv 0..7
    const int no = l & 31, half = l >> 5;
    const float LOG2E = 1.4426950408889634f;

    if (t < M_) {
        int n = t / 9, r = t % 9, ki = r / 3, kj = r % 3;
        pixoff[t] = ((b * NIN_ + n) * H_ + (i + ki)) * W_ + (j + kj);
    }
    // s0 = (1/32) * 3x3 box-sum of SumN
    {
        float s = 0.f;
        const int base = b * 196;
        #pragma unroll
        for (int ki = 0; ki < 3; ++ki)
            #pragma unroll
            for (int kj = 0; kj < 3; ++kj)
                s += bf2f(SumNb[(size_t)(base + (i + ki) * 14 + (j + kj)) * 512 + t]);
        sbufT[t & 15][t >> 4] = s * (1.f / 32.f);
    }
    __syncthreads();
    if (t < NOUT_) {
        float ns = 0.f;
        #pragma unroll
        for (int d = 0; d < DOUT_; ++d) { float s = sbufT[d][t]; ns += s * s; }
        scl[t] = ns / (1.f + ns) * rsqrtf(ns + 1e-16f);
    }
    __syncthreads();
    vvT[t >> 5][t & 31] = sbufT[t >> 5][t & 31] * scl[t & 31];
    __syncthreads();

    float vr[16];
    #pragma unroll
    for (int k = 0; k < 16; ++k) vr[k] = vvT[k][no] * LOG2E;   // log2e * v0

    const int mbase = wv * 36;

// one row: unpack -> dot (dp in log2 units) -> exp2 -> butterfly -> s-acc
#define PROC_ROW(Q0, Q1, ROWIDX)                                              \
    {                                                                         \
        float pv[16];                                                         \
        pv[0]=bflo(Q0.x);  pv[1]=bfhi(Q0.x);  pv[2]=bflo(Q0.y);  pv[3]=bfhi(Q0.y);   \
        pv[4]=bflo(Q0.z);  pv[5]=bfhi(Q0.z);  pv[6]=bflo(Q0.w);  pv[7]=bfhi(Q0.w);   \
        pv[8]=bflo(Q1.x);  pv[9]=bfhi(Q1.x);  pv[10]=bflo(Q1.y); pv[11]=bfhi(Q1.y);  \
        pv[12]=bflo(Q1.z); pv[13]=bfhi(Q1.z); pv[14]=bflo(Q1.w); pv[15]=bfhi(Q1.w);  \
        float d0 = pv[0]*vr[0] + pv[4]*vr[4] + pv[8]*vr[8]  + pv[12]*vr[12];  \
        float d1 = pv[1]*vr[1] + pv[5]*vr[5] + pv[9]*vr[9]  + pv[13]*vr[13];  \
        float d2 = pv[2]*vr[2] + pv[6]*vr[6] + pv[10]*vr[10]+ pv[14]*vr[14];  \
        float d3 = pv[3]*vr[3] + pv[7]*vr[7] + pv[11]*vr[11]+ pv[15]*vr[15];  \
        float dp = (d0 + d1) + (d2 + d3);                                     \
        float e = exp2f(dp);                                                  \
        float S = e;                                                          \
        if (pass == 2) {                                                      \
            float E = e * dp;                                                 \
            _Pragma("unroll")                                                 \
            for (int msk = 16; msk >= 1; msk >>= 1) {                         \
                S += __shfl_xor(S, msk);                                      \
                E += __shfl_xor(E, msk);                                      \
            }                                                                 \
            if (no == 0)                                                      \
                out_ent[(b * M_ + (mbase + (ROWIDX))) * (OH_ * OW_) + ij] =   \
                    0.2f * (log2f(S) - E / S);                                \
            float cc = e * __builtin_amdgcn_rcpf(S);                          \
            _Pragma("unroll")                                                 \
            for (int k = 0; k < 16; ++k) s_acc[k] += cc * pv[k];              \
        } else {                                                              \
            _Pragma("unroll")                                                 \
            for (int msk = 16; msk >= 1; msk >>= 1)                           \
                S += __shfl_xor(S, msk);                                      \
            float cc = e * __builtin_amdgcn_rcpf(S);                          \
            _Pragma("unroll")                                                 \
            for (int k = 0; k < 16; ++k) s_acc[k] += cc * pv[k];              \
        }                                                                     \
    }

    for (int pass = 1; pass <= 2; ++pass) {
        float s_acc[16];
        #pragma unroll
        for (int k = 0; k < 16; ++k) s_acc[k] = 0.f;

        // preload pair g=0: rows half and 2+half
        uint4 c00, c01, c10, c11;
        {
            size_t ba = (size_t)pixoff[mbase + half] * 64 + no * 2;
            c00 = U4[ba]; c01 = U4[ba + 1];
            size_t bb2 = (size_t)pixoff[mbase + 2 + half] * 64 + no * 2;
            c10 = U4[bb2]; c11 = U4[bb2 + 1];
        }
        #pragma clang loop unroll(disable)
        for (int g = 0; g < 9; ++g) {
            uint4 n00 = c00, n01 = c01, n10 = c10, n11 = c11;
            if (g + 1 < 9) {
                size_t ba = (size_t)pixoff[mbase + 4 * (g + 1) + half] * 64 + no * 2;
                n00 = U4[ba]; n01 = U4[ba + 1];
                size_t bb2 = (size_t)pixoff[mbase + 4 * (g + 1) + 2 + half] * 64 + no * 2;
                n10 = U4[bb2]; n11 = U4[bb2 + 1];
            }
            PROC_ROW(c00, c01, 4 * g + half);
            PROC_ROW(c10, c11, 4 * g + 2 + half);
            c00 = n00; c01 = n01; c10 = n10; c11 = n11;
        }

        // wave-internal combine (lane l and l+32 share no), then LDS reduce
        #pragma unroll
        for (int k = 0; k < 16; ++k) s_acc[k] += __shfl_xor(s_acc[k], 32);
        if (half == 0) {
            #pragma unroll
            for (int k = 0; k < 16; ++k) sredT[wv][k][no] = s_acc[k];
        }
        __syncthreads();
        {
            int d = t >> 5, n2 = t & 31;
            float ssm = 0.f;
            #pragma unroll
            for (int h2 = 0; h2 < 8; ++h2) ssm += sredT[h2][d][n2];
            sbufT[d][n2] = ssm;
        }
        __syncthreads();
        if (t < NOUT_) {
            float ns = 0.f;
            #pragma unroll
            for (int d = 0; d < DOUT_; ++d) { float s = sbufT[d][t]; ns += s * s; }
            scl[t] = ns / (1.f + ns) * rsqrtf(ns + 1e-16f);
        }
        __syncthreads();
        vvT[t >> 5][t & 31] = sbufT[t >> 5][t & 31] * scl[t & 31];
        __syncthreads();

        if (pass == 1) {
            #pragma unroll
            for (int k = 0; k < 16; ++k) vr[k] += vvT[k][no] * LOG2E;  // log2e*(v0+v1)
        }
    }
#undef PROC_ROW

    {   // final v output (vvT holds v2)
        int no2 = t >> 4, d = t & 15;
        out_v[(((b * NOUT_ + no2) * OH_ + i) * OW_ + j) * DOUT_ + d] = vvT[d][no2];
    }
}

extern "C" void kernel_launch(void* const* d_in, const int* in_sizes, int n_in,
                              void* d_out, int out_size, void* d_ws, size_t ws_size,
                              hipStream_t stream) {
    const float* x  = (const float*)d_in[0];
    const float* W1 = (const float*)d_in[1];
    const float* b1 = (const float*)d_in[2];
    const float* W2 = (const float*)d_in[3];
    const float* b2 = (const float*)d_in[4];
    const float* W3 = (const float*)d_in[5];
    const float* b3 = (const float*)d_in[6];

    // ws: U (25,690,112 B) | W2B (131,072) | W3B (131,072) | W1B (32,768) | SumN (802,816)
    char* ws = (char*)d_ws;
    __hip_bfloat16* U   = (__hip_bfloat16*)ws;
    __hip_bfloat16* W2B = (__hip_bfloat16*)(ws + (size_t)NPIX_ * PROJ_ * 2);
    __hip_bfloat16* W3B = W2B + (size_t)PROJ_ * HID_;
    __hip_bfloat16* W1B = W3B + (size_t)PROJ_ * HID_;
    unsigned int*   SumNb = (unsigned int*)(W1B + 16384);

    float* out_v   = (float*)d_out;
    float* out_ent = out_v + (size_t)B_ * NOUT_ * OH_ * OW_ * DOUT_;

    hipLaunchKernelGGL(prep_kernel, dim3(256), dim3(256), 0, stream,
                       W1, W2, W3, W1B, W2B, W3B);
    hipLaunchKernelGGL(mlp_mfma_kernel, dim3(NPIX_ / 32), dim3(256), 0, stream,
                       x, (const short8*)W1B, b1, (const short8*)W2B, b2,
                       (const short8*)W3B, b3, U);
    hipLaunchKernelGGL(sumn_kernel, dim3(B_ * H_ * W_), dim3(256), 0, stream,
                       (const unsigned int*)U, SumNb);
    hipLaunchKernelGGL(route_kernel, dim3(B_ * OH_ * OW_), dim3(512), 0, stream,
                       U, (const unsigned short*)SumNb, out_v, out_ent);
}